// Round 8
// baseline (282.001 us; speedup 1.0000x reference)
//
#include <hip/hip_runtime.h>

// Problem constants (fixed by reference setup)
#define B_ 4
#define N_ 96
#define T_ 512
#define G_ 8
#define NIMG (B_*12*T_)   // 24576 images

typedef _Float16 half8 __attribute__((ext_vector_type(8)));
typedef _Float16 half2t __attribute__((ext_vector_type(2)));
typedef float floatx4 __attribute__((ext_vector_type(4)));
typedef float floatx2 __attribute__((ext_vector_type(2)));

// ---------- math helpers ----------
__device__ __forceinline__ float softplusf(float x) {
    return (x > 15.0f) ? x : __logf(1.0f + __expf(x));
}
// branchless softplus (sigma path: args within +-4)
__device__ __forceinline__ float softplus_small(float x) {
    return __logf(1.0f + __expf(x));
}
__device__ __forceinline__ float fast_tanhf(float x) {
    float ax = fabsf(x);
    float e  = __expf(-2.0f * ax);
    float r  = (1.0f - e) * __builtin_amdgcn_rcpf(1.0f + e);
    return copysignf(r, x);
}
// odd Pade(5,4) tanh, |x| <= 1: abs err ~1e-5, no exp (r3-r7 verified)
__device__ __forceinline__ float tanh_pade(float x) {
    float x2 = x * x;
    float num = fmaf(x2, x2 + 105.0f, 945.0f);          // x^4+105x^2+945
    float den = fmaf(x2, fmaf(x2, 15.0f, 420.0f), 945.0f);
    return x * num * __builtin_amdgcn_rcpf(den);
}
// GELU with 3-term Abramowitz-Stegun erf (abs err 2.5e-5)
__device__ __forceinline__ float geluf(float x) {
    float z  = 0.70710678118654752f * x;
    float az = fabsf(z);
    float t  = __builtin_amdgcn_rcpf(fmaf(0.47047f, az, 1.0f));
    float poly = t * fmaf(t, fmaf(t, 0.7478556f, -0.0958798f), 0.3480242f);
    float e  = __expf(-az * az);
    float er = fmaf(-poly, e, 1.0f);     // erf(|z|)
    er = copysignf(er, z);
    return 0.5f * x * (1.0f + er);
}
// force a block-uniform float into an SGPR
__device__ __forceinline__ float rfl(float x) {
    return __int_as_float(__builtin_amdgcn_readfirstlane(__float_as_int(x)));
}

// ---------- K1: splat (r6-proven; barrier-ordered wave-pass reduce) ----------
// grid 768 = (b, k, 16 t-tiles of 32). block (64,4): wave = 32t x 2ch,
// threadIdx.y = n-chunk (24 n each). Reduce = 4 barrier-ordered wave passes
// of plain b128 LDS ops (r6: replaced 16384 LDS atomics, splat 87.8 -> ~30us).
// r8: output layout changed to [64 pix][2 ch] interleaved per image row so the
// CNN staging is one coalesced b32 load per lane.
__global__ __launch_bounds__(256, 3) void splat_kernel(
    const float* __restrict__ mu,  const float* __restrict__ sg0,
    const float* __restrict__ sgv, const float* __restrict__ amp,
    const float* __restrict__ shb, const float* __restrict__ shv,
    const float* __restrict__ p0,  const float* __restrict__ pv,
    const float* __restrict__ tau_raw, const float* __restrict__ da_raw,
    const float* __restrict__ ra, const float* __restrict__ la,
    const float* __restrict__ ll, const float* __restrict__ chest,
    const float* __restrict__ w1, const float* __restrict__ w2,
    _Float16* __restrict__ outp, _Float16* __restrict__ W1p,
    _Float16* __restrict__ W2p) {
    int lx   = threadIdx.x;           // 0..63
    int nc   = threadIdx.y;           // 0..3
    int flat = nc*64 + lx;
    int tt = lx & 31, ch = lx >> 5;
    int Lb = blockIdx.x;
    int t0 = (Lb & 15) << 5;
    int k  = (Lb >> 4) % 12;
    int b  = Lb / 192;

    // ---- weight repack (blocks 0..10 only; trivial extra work) ----
    if (Lb < 10) {
        for (int e = Lb*1152 + flat; e < Lb*1152 + 1152; e += 256) {
            int tap = e/1280, rem = e - tap*1280, co = rem/40, ci = rem - co*40;
            float val = (ci < 32) ? w2[(co*32+ci)*9 + tap] : 0.0f;
            W2p[e] = (_Float16)val;          // [tap][co][ci pad 40]
        }
    } else if (Lb == 10) {
        for (int e = flat; e < 32*40; e += 256) {
            int co = e/40, kk = e - co*40;
            float val = 0.0f;
            if (kk < 18) { int ci = kk & 1, tap = kk >> 1; val = w1[(co*2+ci)*9 + tap]; }
            W1p[e] = (_Float16)val;          // [co][k pad 40]
        }
    }

    // ---- lead constants (block-uniform; hoisted to SGPRs via rfl) ----
    float vx, vy, vz;
    if      (k == 0) { vx = la[0]-ra[0]; vy = la[1]-ra[1]; vz = la[2]-ra[2]; }
    else if (k == 1) { vx = ll[0]-ra[0]; vy = ll[1]-ra[1]; vz = ll[2]-ra[2]; }
    else if (k == 2) { vx = ll[0]-la[0]; vy = ll[1]-la[1]; vz = ll[2]-la[2]; }
    else if (k == 3) { vx = ra[0]-0.5f*(la[0]+ll[0]); vy = ra[1]-0.5f*(la[1]+ll[1]); vz = ra[2]-0.5f*(la[2]+ll[2]); }
    else if (k == 4) { vx = la[0]-0.5f*(ra[0]+ll[0]); vy = la[1]-0.5f*(ra[1]+ll[1]); vz = la[2]-0.5f*(ra[2]+ll[2]); }
    else if (k == 5) { vx = ll[0]-0.5f*(ra[0]+la[0]); vy = ll[1]-0.5f*(ra[1]+la[1]); vz = ll[2]-0.5f*(ra[2]+la[2]); }
    else             { vx = chest[(k-6)*3+0]; vy = chest[(k-6)*3+1]; vz = chest[(k-6)*3+2]; }
    float nn = fmaxf(sqrtf(vx*vx+vy*vy+vz*vz), 1e-6f);
    float Lx = vx/nn, Ly = vy/nn, Lz = vz/nn;
    // e1 = cross(L, x-axis) = (0, Lz, -Ly); if tiny, cross(L, y-axis) = (-Lz, 0, Lx)
    float e1x = 0.0f, e1y = Lz, e1z = -Ly;
    if (sqrtf(e1y*e1y + e1z*e1z) < 1e-4f) { e1x = -Lz; e1y = 0.0f; e1z = Lx; }
    float en = fmaxf(sqrtf(e1x*e1x+e1y*e1y+e1z*e1z), 1e-6f);
    e1x /= en; e1y /= en; e1z /= en;
    float e2x = e1y*Lz - e1z*Ly, e2y = e1z*Lx - e1x*Lz, e2z = e1x*Ly - e1y*Lx;
    float fn = fmaxf(sqrtf(e2x*e2x+e2y*e2y+e2z*e2z), 1e-6f);
    e2x /= fn; e2y /= fn; e2z /= fn;
    Lx = rfl(Lx); Ly = rfl(Ly); Lz = rfl(Lz);
    e1x = rfl(e1x); e1y = rfl(e1y); e1z = rfl(e1z);
    e2x = rfl(e2x); e2y = rfl(e2y); e2z = rfl(e2z);
    float Y[9];
    Y[0] = rfl( 0.282095f);
    Y[1] = rfl(-0.488603f*Ly);
    Y[2] = rfl( 0.488603f*Lz);
    Y[3] = rfl(-0.488603f*Lx);
    Y[4] = rfl( 1.092548f*Lx*Ly);
    Y[5] = rfl(-1.092548f*Ly*Lz);
    Y[6] = rfl( 0.315392f*fmaf(3.0f*Lz, Lz, -1.0f));
    Y[7] = rfl(-1.092548f*Lx*Lz);
    Y[8] = rfl( 0.546274f*(Lx*Lx - Ly*Ly));

    float tau = softplusf(tau_raw[0]) + 0.06f;
    float cc2 = rfl(0.5f/(tau*tau));
    float gamma = rfl(softplusf(da_raw[0]) + 1e-6f);
    const float S = 2.0f/7.0f;   // grid step of linspace(-1,1,8)
    float twoccS = rfl(2.0f*cc2*S);
    // ku[w] = exp(-c(u-g_w)^2) = exp(-c*du^2) * exp(2cS*du)^w * q[w],  du=u+1
    float q[8];
#pragma unroll
    for (int w = 0; w < 8; ++w) { float gw = S*(float)w; q[w] = rfl(__expf(-cc2*gw*gw)); }

    float tf = (float)(t0 + tt) * (1.0f/511.0f);
    floatx2 acc2[32];                 // [h][w/2] packed pairs (v_pk_fma_f32)
#pragma unroll
    for (int i = 0; i < 32; ++i) acc2[i] = (floatx2){0.f, 0.f};

    // ---- main loop: r0-proven body (global per-n loads, no LDS in chain) ----
    int n0 = nc*24;
    for (int n = n0; n < n0+24; ++n) {
        int base = b*N_ + n;
        float dt  = tf - mu[base];
        float sig = softplus_small(fmaf(sgv[base], dt, sg0[base])) + 1e-3f;
        float z   = dt * __builtin_amdgcn_rcpf(sig);
        float gauss = amp[base] * __expf(-0.5f*z*z);
        float prx = fmaf(pv[base*3+0], dt, p0[base*3+0]);
        float pry = fmaf(pv[base*3+1], dt, p0[base*3+1]);
        float prz = fmaf(pv[base*3+2], dt, p0[base*3+2]);
        float nr  = sqrtf(prx*prx + pry*pry + prz*prz);
        float ncl = fmaxf(nr, 1e-8f);
        float th  = fast_tanhf(ncl);
        float scl = th * __builtin_amdgcn_rcpf(ncl);
        float px = prx*scl, py = pry*scl, pz = prz*scl;
        float pn = fmaxf(th, 1e-8f);            // == max(|p_pos|, 1e-8)
        float cosl = (px*Lx + py*Ly + pz*Lz) * __builtin_amdgcn_rcpf(pn);
        float hem  = fmaxf(cosl, 0.0f);
        if (gauss != 0.0f && hem > 0.0f) {
            // acos on [0,1): A-S 4.4.45 poly, abs err 6.7e-5
            float c = fminf(cosl, 0.999999f);
            float s = sqrtf(1.0f - c);
            float theta = s * fmaf(c, fmaf(c, fmaf(c, -0.0187293f, 0.0742610f),
                                   -0.2121144f), 1.5707288f);
            float A = gauss * hem * __expf(-gamma*theta*theta);
            // |dot(p_pos,e)| <= |p_pos| < 1 -> Pade tanh valid
            float uu = tanh_pade(px*e1x + py*e1y + pz*e1z);
            float vv = tanh_pade(px*e2x + py*e2y + pz*e2z);
            float Ach = A;
            if (ch) {                            // sh channel: lanes 32..63
                float shp = 0.0f;
#pragma unroll
                for (int m = 0; m < 9; ++m)
                    shp += fmaf(shv[base*9+m], dt, shb[base*9+m]) * Y[m];
                Ach = A * shp;
            }
            float du = uu + 1.0f, dv = vv + 1.0f;
            float bu = __expf(-cc2*du*du);
            float bv = __expf(-cc2*dv*dv);
            float ru = __expf(twoccS*du);
            float rv = __expf(twoccS*dv);
            floatx2 ku2[4];
            float rw = bu;
#pragma unroll
            for (int w = 0; w < 8; ++w) { ku2[w>>1][w&1] = rw*q[w]; rw *= ru; }
            rw = bv;
#pragma unroll
            for (int h = 0; h < 8; ++h) {
                float tp = (rw*q[h])*Ach; rw *= rv;
                floatx2 tp2 = (floatx2){tp, tp};
#pragma unroll
                for (int w2 = 0; w2 < 4; ++w2)
                    acc2[h*4+w2] = __builtin_elementwise_fma(tp2, ku2[w2], acc2[h*4+w2]);
            }
        }
    }

    // ---- reduce: 4 barrier-ordered wave passes, plain b128 LDS ops ----
    __shared__ float red[32*132];
    int rbase = tt*132 + ch*64;
    if (nc == 0) {
#pragma unroll
        for (int j = 0; j < 16; ++j) {
            floatx4 v = { acc2[2*j][0], acc2[2*j][1], acc2[2*j+1][0], acc2[2*j+1][1] };
            *(floatx4*)&red[rbase + 4*j] = v;
        }
    }
    __syncthreads();
    if (nc == 1) {
#pragma unroll
        for (int j = 0; j < 16; ++j) {
            floatx4 cur = *(const floatx4*)&red[rbase + 4*j];
            cur[0] += acc2[2*j][0]; cur[1] += acc2[2*j][1];
            cur[2] += acc2[2*j+1][0]; cur[3] += acc2[2*j+1][1];
            *(floatx4*)&red[rbase + 4*j] = cur;
        }
    }
    __syncthreads();
    if (nc == 2) {
#pragma unroll
        for (int j = 0; j < 16; ++j) {
            floatx4 cur = *(const floatx4*)&red[rbase + 4*j];
            cur[0] += acc2[2*j][0]; cur[1] += acc2[2*j][1];
            cur[2] += acc2[2*j+1][0]; cur[3] += acc2[2*j+1][1];
            *(floatx4*)&red[rbase + 4*j] = cur;
        }
    }
    __syncthreads();
    if (nc == 3) {
#pragma unroll
        for (int j = 0; j < 16; ++j) {
            floatx4 cur = *(const floatx4*)&red[rbase + 4*j];
            cur[0] += acc2[2*j][0]; cur[1] += acc2[2*j][1];
            cur[2] += acc2[2*j+1][0]; cur[3] += acc2[2*j+1][1];
            *(floatx4*)&red[rbase + 4*j] = cur;
        }
    }
    __syncthreads();

    // write out 32 rows x [64 pix][2 ch] f16 (channel-interleaved for cnn staging)
    int imgbase = (b*12 + k)*T_ + t0;
    int r2 = flat >> 3;           // row (t within tile)
    int pp = (flat & 7) * 8;      // 8-pixel group
    half8 h0, h1;
#pragma unroll
    for (int j = 0; j < 4; ++j) {
        h0[2*j]   = (_Float16)red[r2*132 + pp + j];
        h0[2*j+1] = (_Float16)red[r2*132 + 64 + pp + j];
        h1[2*j]   = (_Float16)red[r2*132 + pp + 4 + j];
        h1[2*j+1] = (_Float16)red[r2*132 + 64 + pp + 4 + j];
    }
    *(half8*)&outp[(imgbase + r2)*128 + pp*2]     = h0;
    *(half8*)&outp[(imgbase + r2)*128 + pp*2 + 8] = h1;
}

// ---------- K2: CNN readout ----------
// 2-wave (128-thread) blocks, 1 image per wave x 4 sequential images,
// grid = 24576/8 = 3072. r7 lesson: duration pinned at 78.4us across two VALU
// budgets with occupancy stuck at ~12 waves/CU -> occupancy-starved + per-image
// overhead repeated 24576x. This round: LDS/block 16.8KB -> 9 blocks/CU = 18
// waves; conv1 weights / biases / fc weights resident across 4 images; next
// image's splat load issued under conv2 (same-wave DS ordering, no barriers);
// fcw pre-scaled by 1/64.
__global__ __launch_bounds__(128, 4) void cnn_kernel(
    const _Float16* __restrict__ splat, const _Float16* __restrict__ W1p,
    const _Float16* __restrict__ W2p,  const float* __restrict__ b1,
    const float* __restrict__ b2,      const float* __restrict__ fcw,
    const float* __restrict__ fcb,     float* __restrict__ outv) {
    __shared__ __align__(16) _Float16 sH1[2][100*40]; // per wave: [10x10 padded pix][ch pad 40]
    __shared__ __align__(16) _Float16 sIn[2][200];    // per wave: [10x10 padded pix][2 ci]
    int wv = threadIdx.y, lane = threadIdx.x;
    int img0 = (blockIdx.x*2 + wv)*4;
    _Float16* H  = sH1[wv];
    _Float16* IN = sIn[wv];
    {   // zero halo regions ONCE (wave-private; persist across the 4 images)
        unsigned long long* hz = (unsigned long long*)H;
        for (int i = lane; i < 1000; i += 64) hz[i] = 0ull;
        unsigned int* iz = (unsigned int*)IN;
        for (int i = lane; i < 100; i += 64) iz[i] = 0u;
    }
    // per-lane staging geometry: lane = pixel; splat row is [pix][2ch] interleaved
    int pstg = lane;
    int inoff = (((pstg>>3)+1)*10 + (pstg&7) + 1)*2;
    // stage first image (coalesced b32 load; ds order after zero ensures halo ok)
    *(unsigned int*)&IN[inoff] = *(const unsigned int*)&splat[img0*128 + pstg*2];

    int r = lane & 15, qd = lane >> 4;
    // resident constants (live across all 4 images)
    floatx4 b14[2], b24[2], fw4[2];
#pragma unroll
    for (int nt = 0; nt < 2; ++nt) {
        int cb = nt*16 + qd*4;
        b14[nt] = *(const floatx4*)&b1[cb];
        b24[nt] = *(const floatx4*)&b2[cb];
        floatx4 f = *(const floatx4*)&fcw[cb];
        f[0] *= (1.0f/64.0f); f[1] *= (1.0f/64.0f);
        f[2] *= (1.0f/64.0f); f[3] *= (1.0f/64.0f);
        fw4[nt] = f;
    }
    half8 bw[2];
#pragma unroll
    for (int nt = 0; nt < 2; ++nt)
        bw[nt] = *(const half8*)&W1p[(nt*16+r)*40 + qd*8];

    for (int it = 0; it < 4; ++it) {
        int img = img0 + it;
        // ---- conv1: D[ch][pix] via mfma(W, In, C=bias) ----
        floatx4 c1[2][4];
#pragma unroll
        for (int nt = 0; nt < 2; ++nt)
#pragma unroll
          for (int mt = 0; mt < 4; ++mt) c1[nt][mt] = b14[nt];
#pragma unroll
        for (int mt = 0; mt < 4; ++mt) {
            int p = mt*16 + r, py = p>>3, px = p&7;
            half8 a;
#pragma unroll
            for (int m = 0; m < 4; ++m) {
                int tap = qd*4 + m;                    // kk = 2*tap + ci
                int tc  = (tap > 8) ? 8 : tap;         // clamp keeps address in-bounds
                int ky = tc/3, kx = tc - ky*3;
                half2t pr = *(const half2t*)&IN[((py+ky)*10 + (px+kx))*2];
                if (tap >= 9) { pr[0] = (_Float16)0.0f; pr[1] = (_Float16)0.0f; }
                a[2*m]   = pr[0];
                a[2*m+1] = pr[1];
            }
#pragma unroll
            for (int nt = 0; nt < 2; ++nt)
                c1[nt][mt] = __builtin_amdgcn_mfma_f32_16x16x32_f16(bw[nt], a, c1[nt][mt], 0, 0, 0);
        }
        // prefetch next image's staging word (latency hides under gelu+conv2)
        unsigned int nxt = 0u;
        if (it < 3) nxt = *(const unsigned int*)&splat[(img+1)*128 + pstg*2];
        // gelu -> H[pix][ch]: thread holds 4 consecutive channels at pixel mt*16+r
#pragma unroll
        for (int nt = 0; nt < 2; ++nt)
#pragma unroll
          for (int mt = 0; mt < 4; ++mt) {
            int p = mt*16 + r, py = p>>3, px = p&7;
            int hb = ((py+1)*10 + (px+1))*40 + nt*16 + qd*4;
            half2t h01, h23;
            h01[0] = (_Float16)geluf(c1[nt][mt][0]);
            h01[1] = (_Float16)geluf(c1[nt][mt][1]);
            h23[0] = (_Float16)geluf(c1[nt][mt][2]);
            h23[1] = (_Float16)geluf(c1[nt][mt][3]);
            *(half2t*)&H[hb]     = h01;
            *(half2t*)&H[hb + 2] = h23;
          }
        // ---- conv2: D[ch][pix] via mfma(W, H, C=bias), K=288 (9 taps x 32 ch) ----
        floatx4 c2[2][4];
#pragma unroll
        for (int nt = 0; nt < 2; ++nt)
#pragma unroll
          for (int mt = 0; mt < 4; ++mt) c2[nt][mt] = b24[nt];
#pragma unroll
        for (int tap = 0; tap < 9; ++tap) {
            int ky = tap/3, kx = tap - (tap/3)*3;
            half8 wb[2];
#pragma unroll
            for (int nt = 0; nt < 2; ++nt)
                wb[nt] = *(const half8*)&W2p[tap*1280 + (nt*16+r)*40 + qd*8];
#pragma unroll
            for (int mt = 0; mt < 4; ++mt) {
                int p = mt*16 + r, py = p>>3, px = p&7;
                half8 a = *(const half8*)&H[((py+ky)*10 + (px+kx))*40 + qd*8];
#pragma unroll
                for (int nt = 0; nt < 2; ++nt)
                    c2[nt][mt] = __builtin_amdgcn_mfma_f32_16x16x32_f16(wb[nt], a, c2[nt][mt], 0, 0, 0);
            }
        }
        // write next image's staging word (conv1 of it+1 reads it; DS pipe ordered)
        if (it < 3) *(unsigned int*)&IN[inoff] = nxt;
        // gelu + fc-weighted pool (fcw pre-scaled by 1/64)
        float tot = 0.f;
#pragma unroll
        for (int nt = 0; nt < 2; ++nt)
#pragma unroll
          for (int mt = 0; mt < 4; ++mt)
#pragma unroll
            for (int j = 0; j < 4; ++j)
                tot = fmaf(geluf(c2[nt][mt][j]), fw4[nt][j], tot);
        tot += __shfl_xor(tot, 1);  tot += __shfl_xor(tot, 2);
        tot += __shfl_xor(tot, 4);  tot += __shfl_xor(tot, 8);
        tot += __shfl_xor(tot, 16); tot += __shfl_xor(tot, 32);
        tot += fcb[0];
        if (lane == 0) {
            int t = img & 511, bk = img >> 9;
            int kk = bk % 12, bb = bk / 12;
            // faithful torch permutation: out[b, :, :].flat = scalars[b].T.flat
            outv[(bb*T_ + t)*12 + kk] = tot;
        }
    }
}

extern "C" void kernel_launch(void* const* d_in, const int* in_sizes, int n_in,
                              void* d_out, int out_size, void* d_ws, size_t ws_size,
                              hipStream_t stream) {
    const float* mu   = (const float*)d_in[0];
    const float* sg0  = (const float*)d_in[1];
    const float* sgv  = (const float*)d_in[2];
    const float* amp  = (const float*)d_in[3];
    const float* shb  = (const float*)d_in[4];
    const float* shv  = (const float*)d_in[5];
    const float* p0   = (const float*)d_in[6];
    const float* pvel = (const float*)d_in[7];
    const float* taur = (const float*)d_in[8];
    const float* dar  = (const float*)d_in[9];
    const float* ra   = (const float*)d_in[10];
    const float* la   = (const float*)d_in[11];
    const float* ll   = (const float*)d_in[12];
    const float* chest= (const float*)d_in[13];
    const float* w1   = (const float*)d_in[14];
    const float* b1   = (const float*)d_in[15];
    const float* w2   = (const float*)d_in[16];
    const float* b2   = (const float*)d_in[17];
    const float* fcw  = (const float*)d_in[18];
    const float* fcb  = (const float*)d_in[19];

    char* ws = (char*)d_ws;
    _Float16*  W1p   = (_Float16*)ws;            // 2560 B
    _Float16*  W2p   = (_Float16*)(ws + 4096);   // 23040 B
    _Float16*  splat = (_Float16*)(ws + 32768);  // 6.29 MB

    splat_kernel<<<768, dim3(64,4), 0, stream>>>(mu, sg0, sgv, amp, shb, shv, p0, pvel,
                                                 taur, dar, ra, la, ll, chest, w1, w2,
                                                 splat, W1p, W2p);
    cnn_kernel<<<NIMG/8, dim3(64,2), 0, stream>>>(splat, W1p, W2p, b1, b2, fcw, fcb,
                                                  (float*)d_out);
}

// Round 9
// 187.585 us; speedup vs baseline: 1.5033x; 1.5033x over previous
//
#include <hip/hip_runtime.h>

// Problem constants (fixed by reference setup)
#define B_ 4
#define N_ 96
#define T_ 512
#define G_ 8
#define NIMG (B_*12*T_)   // 24576 images

typedef _Float16 half8 __attribute__((ext_vector_type(8)));
typedef _Float16 half2t __attribute__((ext_vector_type(2)));
typedef float floatx4 __attribute__((ext_vector_type(4)));
typedef float floatx2 __attribute__((ext_vector_type(2)));
typedef unsigned int uintx4 __attribute__((ext_vector_type(4)));

// ---------- math helpers ----------
__device__ __forceinline__ float softplusf(float x) {
    return (x > 15.0f) ? x : __logf(1.0f + __expf(x));
}
// branchless softplus (sigma path: args within +-4)
__device__ __forceinline__ float softplus_small(float x) {
    return __logf(1.0f + __expf(x));
}
__device__ __forceinline__ float fast_tanhf(float x) {
    float ax = fabsf(x);
    float e  = __expf(-2.0f * ax);
    float r  = (1.0f - e) * __builtin_amdgcn_rcpf(1.0f + e);
    return copysignf(r, x);
}
// odd Pade(5,4) tanh, |x| <= 1: abs err ~1e-5, no exp (r3-r8 verified)
__device__ __forceinline__ float tanh_pade(float x) {
    float x2 = x * x;
    float num = fmaf(x2, x2 + 105.0f, 945.0f);          // x^4+105x^2+945
    float den = fmaf(x2, fmaf(x2, 15.0f, 420.0f), 945.0f);
    return x * num * __builtin_amdgcn_rcpf(den);
}
// Packed-pair GELU, same A-S 3-term erf math as the r0-r8 scalar version,
// restructured as 0.5x + 0.5|x|*erf(|z|) (identical for both signs, no
// copysign). Non-trans ops go 2-wide via v_pk_*; rcp/exp stay scalar trans.
__device__ __forceinline__ floatx2 gelu2(floatx2 x) {
    floatx2 one = {1.0f, 1.0f};
    floatx2 ax  = __builtin_elementwise_max(x, -x);                 // |x|
    // t = 1/(1 + 0.47047*|z|), z = 0.70710678*x -> coeff 0.33267049
    floatx2 td  = __builtin_elementwise_fma((floatx2){0.33267049f, 0.33267049f}, ax, one);
    floatx2 t;
    t[0] = __builtin_amdgcn_rcpf(td[0]);
    t[1] = __builtin_amdgcn_rcpf(td[1]);
    floatx2 poly = t * __builtin_elementwise_fma(t,
                     __builtin_elementwise_fma(t, (floatx2){0.7478556f, 0.7478556f},
                                               (floatx2){-0.0958798f, -0.0958798f}),
                     (floatx2){0.3480242f, 0.3480242f});
    floatx2 m  = x * x;
    floatx2 em = m * (floatx2){-0.5f, -0.5f};                        // -z^2
    floatx2 e;
    e[0] = __expf(em[0]);
    e[1] = __expf(em[1]);
    floatx2 er  = __builtin_elementwise_fma(-poly, e, one);          // erf(|z|)
    floatx2 hx  = x  * (floatx2){0.5f, 0.5f};
    floatx2 hax = ax * (floatx2){0.5f, 0.5f};
    return __builtin_elementwise_fma(hax, er, hx);                   // 0.5x + 0.5|x|*erf
}
// force a block-uniform float into an SGPR
__device__ __forceinline__ float rfl(float x) {
    return __int_as_float(__builtin_amdgcn_readfirstlane(__float_as_int(x)));
}

// ---------- K1: splat (r6-proven reduce; r8-verified interleaved output) ----------
// grid 768 = (b, k, 16 t-tiles of 32). block (64,4): wave = 32t x 2ch,
// threadIdx.y = n-chunk (24 n each). Reduce = 4 barrier-ordered wave passes
// of plain b128 LDS ops (r6: replaced 16384 LDS atomics, splat 87.8 -> ~30us).
// Output layout [64 pix][2 ch] interleaved so CNN staging is one b32/lane.
__global__ __launch_bounds__(256, 3) void splat_kernel(
    const float* __restrict__ mu,  const float* __restrict__ sg0,
    const float* __restrict__ sgv, const float* __restrict__ amp,
    const float* __restrict__ shb, const float* __restrict__ shv,
    const float* __restrict__ p0,  const float* __restrict__ pv,
    const float* __restrict__ tau_raw, const float* __restrict__ da_raw,
    const float* __restrict__ ra, const float* __restrict__ la,
    const float* __restrict__ ll, const float* __restrict__ chest,
    const float* __restrict__ w1, const float* __restrict__ w2,
    _Float16* __restrict__ outp, _Float16* __restrict__ W1p,
    _Float16* __restrict__ W2p) {
    int lx   = threadIdx.x;           // 0..63
    int nc   = threadIdx.y;           // 0..3
    int flat = nc*64 + lx;
    int tt = lx & 31, ch = lx >> 5;
    int Lb = blockIdx.x;
    int t0 = (Lb & 15) << 5;
    int k  = (Lb >> 4) % 12;
    int b  = Lb / 192;

    // ---- weight repack (blocks 0..10 only; trivial extra work) ----
    if (Lb < 10) {
        for (int e = Lb*1152 + flat; e < Lb*1152 + 1152; e += 256) {
            int tap = e/1280, rem = e - tap*1280, co = rem/40, ci = rem - co*40;
            float val = (ci < 32) ? w2[(co*32+ci)*9 + tap] : 0.0f;
            W2p[e] = (_Float16)val;          // [tap][co][ci pad 40]
        }
    } else if (Lb == 10) {
        for (int e = flat; e < 32*40; e += 256) {
            int co = e/40, kk = e - co*40;
            float val = 0.0f;
            if (kk < 18) { int ci = kk & 1, tap = kk >> 1; val = w1[(co*2+ci)*9 + tap]; }
            W1p[e] = (_Float16)val;          // [co][k pad 40]
        }
    }

    // ---- lead constants (block-uniform; hoisted to SGPRs via rfl) ----
    float vx, vy, vz;
    if      (k == 0) { vx = la[0]-ra[0]; vy = la[1]-ra[1]; vz = la[2]-ra[2]; }
    else if (k == 1) { vx = ll[0]-ra[0]; vy = ll[1]-ra[1]; vz = ll[2]-ra[2]; }
    else if (k == 2) { vx = ll[0]-la[0]; vy = ll[1]-la[1]; vz = ll[2]-la[2]; }
    else if (k == 3) { vx = ra[0]-0.5f*(la[0]+ll[0]); vy = ra[1]-0.5f*(la[1]+ll[1]); vz = ra[2]-0.5f*(la[2]+ll[2]); }
    else if (k == 4) { vx = la[0]-0.5f*(ra[0]+ll[0]); vy = la[1]-0.5f*(ra[1]+ll[1]); vz = la[2]-0.5f*(ra[2]+ll[2]); }
    else if (k == 5) { vx = ll[0]-0.5f*(ra[0]+la[0]); vy = ll[1]-0.5f*(ra[1]+la[1]); vz = ll[2]-0.5f*(ra[2]+la[2]); }
    else             { vx = chest[(k-6)*3+0]; vy = chest[(k-6)*3+1]; vz = chest[(k-6)*3+2]; }
    float nn = fmaxf(sqrtf(vx*vx+vy*vy+vz*vz), 1e-6f);
    float Lx = vx/nn, Ly = vy/nn, Lz = vz/nn;
    // e1 = cross(L, x-axis) = (0, Lz, -Ly); if tiny, cross(L, y-axis) = (-Lz, 0, Lx)
    float e1x = 0.0f, e1y = Lz, e1z = -Ly;
    if (sqrtf(e1y*e1y + e1z*e1z) < 1e-4f) { e1x = -Lz; e1y = 0.0f; e1z = Lx; }
    float en = fmaxf(sqrtf(e1x*e1x+e1y*e1y+e1z*e1z), 1e-6f);
    e1x /= en; e1y /= en; e1z /= en;
    float e2x = e1y*Lz - e1z*Ly, e2y = e1z*Lx - e1x*Lz, e2z = e1x*Ly - e1y*Lx;
    float fn = fmaxf(sqrtf(e2x*e2x+e2y*e2y+e2z*e2z), 1e-6f);
    e2x /= fn; e2y /= fn; e2z /= fn;
    Lx = rfl(Lx); Ly = rfl(Ly); Lz = rfl(Lz);
    e1x = rfl(e1x); e1y = rfl(e1y); e1z = rfl(e1z);
    e2x = rfl(e2x); e2y = rfl(e2y); e2z = rfl(e2z);
    float Y[9];
    Y[0] = rfl( 0.282095f);
    Y[1] = rfl(-0.488603f*Ly);
    Y[2] = rfl( 0.488603f*Lz);
    Y[3] = rfl(-0.488603f*Lx);
    Y[4] = rfl( 1.092548f*Lx*Ly);
    Y[5] = rfl(-1.092548f*Ly*Lz);
    Y[6] = rfl( 0.315392f*fmaf(3.0f*Lz, Lz, -1.0f));
    Y[7] = rfl(-1.092548f*Lx*Lz);
    Y[8] = rfl( 0.546274f*(Lx*Lx - Ly*Ly));

    float tau = softplusf(tau_raw[0]) + 0.06f;
    float cc2 = rfl(0.5f/(tau*tau));
    float gamma = rfl(softplusf(da_raw[0]) + 1e-6f);
    const float S = 2.0f/7.0f;   // grid step of linspace(-1,1,8)
    float twoccS = rfl(2.0f*cc2*S);
    // ku[w] = exp(-c(u-g_w)^2) = exp(-c*du^2) * exp(2cS*du)^w * q[w],  du=u+1
    float q[8];
#pragma unroll
    for (int w = 0; w < 8; ++w) { float gw = S*(float)w; q[w] = rfl(__expf(-cc2*gw*gw)); }

    float tf = (float)(t0 + tt) * (1.0f/511.0f);
    floatx2 acc2[32];                 // [h][w/2] packed pairs (v_pk_fma_f32)
#pragma unroll
    for (int i = 0; i < 32; ++i) acc2[i] = (floatx2){0.f, 0.f};

    // ---- main loop: r0-proven body (global per-n loads, no LDS in chain) ----
    int n0 = nc*24;
    for (int n = n0; n < n0+24; ++n) {
        int base = b*N_ + n;
        float dt  = tf - mu[base];
        float sig = softplus_small(fmaf(sgv[base], dt, sg0[base])) + 1e-3f;
        float z   = dt * __builtin_amdgcn_rcpf(sig);
        float gauss = amp[base] * __expf(-0.5f*z*z);
        float prx = fmaf(pv[base*3+0], dt, p0[base*3+0]);
        float pry = fmaf(pv[base*3+1], dt, p0[base*3+1]);
        float prz = fmaf(pv[base*3+2], dt, p0[base*3+2]);
        float nr  = sqrtf(prx*prx + pry*pry + prz*prz);
        float ncl = fmaxf(nr, 1e-8f);
        float th  = fast_tanhf(ncl);
        float scl = th * __builtin_amdgcn_rcpf(ncl);
        float px = prx*scl, py = pry*scl, pz = prz*scl;
        float pn = fmaxf(th, 1e-8f);            // == max(|p_pos|, 1e-8)
        float cosl = (px*Lx + py*Ly + pz*Lz) * __builtin_amdgcn_rcpf(pn);
        float hem  = fmaxf(cosl, 0.0f);
        if (gauss != 0.0f && hem > 0.0f) {
            // acos on [0,1): A-S 4.4.45 poly, abs err 6.7e-5
            float c = fminf(cosl, 0.999999f);
            float s = sqrtf(1.0f - c);
            float theta = s * fmaf(c, fmaf(c, fmaf(c, -0.0187293f, 0.0742610f),
                                   -0.2121144f), 1.5707288f);
            float A = gauss * hem * __expf(-gamma*theta*theta);
            // |dot(p_pos,e)| <= |p_pos| < 1 -> Pade tanh valid
            float uu = tanh_pade(px*e1x + py*e1y + pz*e1z);
            float vv = tanh_pade(px*e2x + py*e2y + pz*e2z);
            float Ach = A;
            if (ch) {                            // sh channel: lanes 32..63
                float shp = 0.0f;
#pragma unroll
                for (int m = 0; m < 9; ++m)
                    shp += fmaf(shv[base*9+m], dt, shb[base*9+m]) * Y[m];
                Ach = A * shp;
            }
            float du = uu + 1.0f, dv = vv + 1.0f;
            float bu = __expf(-cc2*du*du);
            float bv = __expf(-cc2*dv*dv);
            float ru = __expf(twoccS*du);
            float rv = __expf(twoccS*dv);
            floatx2 ku2[4];
            float rw = bu;
#pragma unroll
            for (int w = 0; w < 8; ++w) { ku2[w>>1][w&1] = rw*q[w]; rw *= ru; }
            rw = bv;
#pragma unroll
            for (int h = 0; h < 8; ++h) {
                float tp = (rw*q[h])*Ach; rw *= rv;
                floatx2 tp2 = (floatx2){tp, tp};
#pragma unroll
                for (int w2 = 0; w2 < 4; ++w2)
                    acc2[h*4+w2] = __builtin_elementwise_fma(tp2, ku2[w2], acc2[h*4+w2]);
            }
        }
    }

    // ---- reduce: 4 barrier-ordered wave passes, plain b128 LDS ops ----
    __shared__ float red[32*132];
    int rbase = tt*132 + ch*64;
    if (nc == 0) {
#pragma unroll
        for (int j = 0; j < 16; ++j) {
            floatx4 v = { acc2[2*j][0], acc2[2*j][1], acc2[2*j+1][0], acc2[2*j+1][1] };
            *(floatx4*)&red[rbase + 4*j] = v;
        }
    }
    __syncthreads();
    if (nc == 1) {
#pragma unroll
        for (int j = 0; j < 16; ++j) {
            floatx4 cur = *(const floatx4*)&red[rbase + 4*j];
            cur[0] += acc2[2*j][0]; cur[1] += acc2[2*j][1];
            cur[2] += acc2[2*j+1][0]; cur[3] += acc2[2*j+1][1];
            *(floatx4*)&red[rbase + 4*j] = cur;
        }
    }
    __syncthreads();
    if (nc == 2) {
#pragma unroll
        for (int j = 0; j < 16; ++j) {
            floatx4 cur = *(const floatx4*)&red[rbase + 4*j];
            cur[0] += acc2[2*j][0]; cur[1] += acc2[2*j][1];
            cur[2] += acc2[2*j+1][0]; cur[3] += acc2[2*j+1][1];
            *(floatx4*)&red[rbase + 4*j] = cur;
        }
    }
    __syncthreads();
    if (nc == 3) {
#pragma unroll
        for (int j = 0; j < 16; ++j) {
            floatx4 cur = *(const floatx4*)&red[rbase + 4*j];
            cur[0] += acc2[2*j][0]; cur[1] += acc2[2*j][1];
            cur[2] += acc2[2*j+1][0]; cur[3] += acc2[2*j+1][1];
            *(floatx4*)&red[rbase + 4*j] = cur;
        }
    }
    __syncthreads();

    // write out 32 rows x [64 pix][2 ch] f16 (channel-interleaved, r8-verified)
    int imgbase = (b*12 + k)*T_ + t0;
    int r2 = flat >> 3;           // row (t within tile)
    int pp = (flat & 7) * 8;      // 8-pixel group
    half8 h0, h1;
#pragma unroll
    for (int j = 0; j < 4; ++j) {
        h0[2*j]   = (_Float16)red[r2*132 + pp + j];
        h0[2*j+1] = (_Float16)red[r2*132 + 64 + pp + j];
        h1[2*j]   = (_Float16)red[r2*132 + pp + 4 + j];
        h1[2*j+1] = (_Float16)red[r2*132 + 64 + pp + 4 + j];
    }
    *(half8*)&outp[(imgbase + r2)*128 + pp*2]     = h0;
    *(half8*)&outp[(imgbase + r2)*128 + pp*2 + 8] = h1;
}

// ---------- K2: CNN readout ----------
// r7 shell (proven 78.4us): 1 wave/image, 3 img per 192-thread block, grid 8192,
// no barriers (wave-private LDS, same-wave DS pipe ordering). r9 VALU cuts:
// packed-pair gelu2, conv1 gather via hoisted koff[] + zero-tail (no clamps /
// cndmask / inserts), fcw pre-scaled by 1/64 with packed pool fma.
// r8 lesson: NO multi-image register loop (spilled at the 128-reg cap).
__global__ __launch_bounds__(192, 4) void cnn_kernel(
    const _Float16* __restrict__ splat, const _Float16* __restrict__ W1p,
    const _Float16* __restrict__ W2p,  const float* __restrict__ b1,
    const float* __restrict__ b2,      const float* __restrict__ fcw,
    const float* __restrict__ fcb,     float* __restrict__ outv) {
    __shared__ __align__(16) _Float16 sH1[3][100*40]; // per img: [10x10 padded pix][ch pad 40]
    __shared__ __align__(16) _Float16 sIn[3][408];    // per img: [10x10 pix][2 ci] + zero tail
    int wv = threadIdx.y, lane = threadIdx.x;
    int img = blockIdx.x*3 + wv;
    _Float16* H  = sH1[wv];
    _Float16* IN = sIn[wv];
    {   // zero H halo + ALL of IN incl. the tail used by invalid conv1 taps
        unsigned long long* hz = (unsigned long long*)H;
        for (int i = lane; i < 1000; i += 64) hz[i] = 0ull;
        unsigned int* iz = (unsigned int*)IN;
        for (int i = lane; i < 204; i += 64) iz[i] = 0u;
    }
    // stage input: lane = pixel; splat row is [pix][2ch] interleaved -> 1 b32
    *(unsigned int*)&IN[(((lane>>3)+1)*10 + (lane&7) + 1)*2] =
        *(const unsigned int*)&splat[img*128 + lane*2];

    int r = lane & 15, qd = lane >> 4;
    // conv1 tap offsets (hoisted; invalid taps land in the zero tail >=200)
    int koff[4];
#pragma unroll
    for (int m = 0; m < 4; ++m) {
        int tap = qd*4 + m;
        int ky = tap/3, kx = tap - (tap/3)*3;
        koff[m] = (tap < 9) ? (ky*10 + kx)*2 : 224;
    }
    // per-thread channel-row constants (channels nt*16 + qd*4 + j)
    floatx4 b14[2], b24[2];
    floatx2 fwlo[2], fwhi[2];
#pragma unroll
    for (int nt = 0; nt < 2; ++nt) {
        int cb = nt*16 + qd*4;
        b14[nt] = *(const floatx4*)&b1[cb];
        b24[nt] = *(const floatx4*)&b2[cb];
        floatx4 f = *(const floatx4*)&fcw[cb];
        fwlo[nt] = (floatx2){f[0]*(1.0f/64.0f), f[1]*(1.0f/64.0f)};
        fwhi[nt] = (floatx2){f[2]*(1.0f/64.0f), f[3]*(1.0f/64.0f)};
    }
    half8 bw[2];
#pragma unroll
    for (int nt = 0; nt < 2; ++nt)
        bw[nt] = *(const half8*)&W1p[(nt*16+r)*40 + qd*8];

    // ---- conv1: D[ch][pix] via mfma(W, In, C=bias) ----
    floatx4 c1[2][4];
#pragma unroll
    for (int nt = 0; nt < 2; ++nt)
#pragma unroll
      for (int mt = 0; mt < 4; ++mt) c1[nt][mt] = b14[nt];
#pragma unroll
    for (int mt = 0; mt < 4; ++mt) {
        int p = mt*16 + r, py = p>>3, px = p&7;
        int pixbase = (py*10 + px)*2;
        uintx4 au;
#pragma unroll
        for (int m = 0; m < 4; ++m)
            au[m] = *(const unsigned int*)&IN[pixbase + koff[m]];
        half8 a = __builtin_bit_cast(half8, au);
#pragma unroll
        for (int nt = 0; nt < 2; ++nt)
            c1[nt][mt] = __builtin_amdgcn_mfma_f32_16x16x32_f16(bw[nt], a, c1[nt][mt], 0, 0, 0);
    }
    // packed gelu -> H[pix][ch]: thread holds 4 consecutive channels per pixel
#pragma unroll
    for (int nt = 0; nt < 2; ++nt)
#pragma unroll
      for (int mt = 0; mt < 4; ++mt) {
        int p = mt*16 + r, py = p>>3, px = p&7;
        int hb = ((py+1)*10 + (px+1))*40 + nt*16 + qd*4;
        floatx2 g01 = gelu2((floatx2){c1[nt][mt][0], c1[nt][mt][1]});
        floatx2 g23 = gelu2((floatx2){c1[nt][mt][2], c1[nt][mt][3]});
        half2t h01, h23;
        h01[0] = (_Float16)g01[0]; h01[1] = (_Float16)g01[1];
        h23[0] = (_Float16)g23[0]; h23[1] = (_Float16)g23[1];
        *(half2t*)&H[hb]     = h01;
        *(half2t*)&H[hb + 2] = h23;
      }

    // ---- conv2: D[ch][pix] via mfma(W, H, C=bias), K=288 (9 taps x 32 ch) ----
    floatx4 c2[2][4];
#pragma unroll
    for (int nt = 0; nt < 2; ++nt)
#pragma unroll
      for (int mt = 0; mt < 4; ++mt) c2[nt][mt] = b24[nt];
#pragma unroll
    for (int tap = 0; tap < 9; ++tap) {
        int ky = tap/3, kx = tap - (tap/3)*3;
        half8 wb[2];
#pragma unroll
        for (int nt = 0; nt < 2; ++nt)
            wb[nt] = *(const half8*)&W2p[tap*1280 + (nt*16+r)*40 + qd*8];
#pragma unroll
        for (int mt = 0; mt < 4; ++mt) {
            int p = mt*16 + r, py = p>>3, px = p&7;
            half8 a = *(const half8*)&H[((py+ky)*10 + (px+kx))*40 + qd*8];
#pragma unroll
            for (int nt = 0; nt < 2; ++nt)
                c2[nt][mt] = __builtin_amdgcn_mfma_f32_16x16x32_f16(wb[nt], a, c2[nt][mt], 0, 0, 0);
        }
    }
    // packed gelu + fc-weighted pool (fcw pre-scaled by 1/64)
    floatx2 tot2 = {0.f, 0.f};
#pragma unroll
    for (int nt = 0; nt < 2; ++nt)
#pragma unroll
      for (int mt = 0; mt < 4; ++mt) {
        floatx2 g01 = gelu2((floatx2){c2[nt][mt][0], c2[nt][mt][1]});
        floatx2 g23 = gelu2((floatx2){c2[nt][mt][2], c2[nt][mt][3]});
        tot2 = __builtin_elementwise_fma(g01, fwlo[nt], tot2);
        tot2 = __builtin_elementwise_fma(g23, fwhi[nt], tot2);
      }
    float tot = tot2[0] + tot2[1];
    tot += __shfl_xor(tot, 1);  tot += __shfl_xor(tot, 2);
    tot += __shfl_xor(tot, 4);  tot += __shfl_xor(tot, 8);
    tot += __shfl_xor(tot, 16); tot += __shfl_xor(tot, 32);
    tot += fcb[0];
    if (lane == 0) {
        int t = img & 511, bk = img >> 9;
        int kk = bk % 12, bb = bk / 12;
        // faithful torch permutation: out[b, :, :].flat = scalars[b].T.flat
        outv[(bb*T_ + t)*12 + kk] = tot;
    }
}

extern "C" void kernel_launch(void* const* d_in, const int* in_sizes, int n_in,
                              void* d_out, int out_size, void* d_ws, size_t ws_size,
                              hipStream_t stream) {
    const float* mu   = (const float*)d_in[0];
    const float* sg0  = (const float*)d_in[1];
    const float* sgv  = (const float*)d_in[2];
    const float* amp  = (const float*)d_in[3];
    const float* shb  = (const float*)d_in[4];
    const float* shv  = (const float*)d_in[5];
    const float* p0   = (const float*)d_in[6];
    const float* pvel = (const float*)d_in[7];
    const float* taur = (const float*)d_in[8];
    const float* dar  = (const float*)d_in[9];
    const float* ra   = (const float*)d_in[10];
    const float* la   = (const float*)d_in[11];
    const float* ll   = (const float*)d_in[12];
    const float* chest= (const float*)d_in[13];
    const float* w1   = (const float*)d_in[14];
    const float* b1   = (const float*)d_in[15];
    const float* w2   = (const float*)d_in[16];
    const float* b2   = (const float*)d_in[17];
    const float* fcw  = (const float*)d_in[18];
    const float* fcb  = (const float*)d_in[19];

    char* ws = (char*)d_ws;
    _Float16*  W1p   = (_Float16*)ws;            // 2560 B
    _Float16*  W2p   = (_Float16*)(ws + 4096);   // 23040 B
    _Float16*  splat = (_Float16*)(ws + 32768);  // 6.29 MB

    splat_kernel<<<768, dim3(64,4), 0, stream>>>(mu, sg0, sgv, amp, shb, shv, p0, pvel,
                                                 taur, dar, ra, la, ll, chest, w1, w2,
                                                 splat, W1p, W2p);
    cnn_kernel<<<NIMG/3, dim3(64,3), 0, stream>>>(splat, W1p, W2p, b1, b2, fcw, fcb,
                                                  (float*)d_out);
}